// Round 18
// baseline (141.280 us; speedup 1.0000x reference)
//
#include <hip/hip_runtime.h>
#include <stdint.h>

typedef _Float16 h8 __attribute__((ext_vector_type(8)));
typedef _Float16 h4 __attribute__((ext_vector_type(4)));
typedef float f32x4 __attribute__((ext_vector_type(4)));
typedef float f32x16 __attribute__((ext_vector_type(16)));
typedef uint32_t u32x4 __attribute__((ext_vector_type(4)));

#if __has_builtin(__builtin_amdgcn_exp2f)
#define EXP2(x) __builtin_amdgcn_exp2f(x)
#else
#define EXP2(x) exp2f(x)
#endif

#if __has_builtin(__builtin_amdgcn_permlane32_swap)
#define HAVE_PLSWAP 1
#else
#define HAVE_PLSWAP 0
#endif

// workspace map (total <= 51380224 bytes)
#define WS_PWH  0u          // _Float16 [128][1024]  (dead after fg1; mlm overwrites)
#define WS_WH   262144u     // _Float16 [384][128]   (dead after gemm2)
#define WS_BC   600064u     // float [384]
#define WS_F2D  1048576u    // _Float16 [4][4096][128] dense (dead after gemm2)
#define WS_OP   5242880u    // _Float16 [32 pb][128 d][4096 n] normalized partial O
#define WS_QKVT 38797312u   // _Float16 [4][4096][256] q|k, 512B rows
#define WS_VT   47185920u   // _Float16 [4][128][4096] v, d-major
#define WS_MLM  0u          // float [32][4096] running max (log2 domain)
#define WS_MLL  524288u     // float [32][4096] running sum

__device__ __forceinline__ void gll16(const void* g, void* l) {
  __builtin_amdgcn_global_load_lds((const __attribute__((address_space(1))) unsigned int*)g,
                                   (__attribute__((address_space(3))) unsigned int*)l, 16, 0, 0);
}

// ---------------- kernel 0: casts; bias bc = b + W*pb via one WAVE per o ----------------
__global__ void k_cvt(const float* __restrict__ pw, const float* __restrict__ pb,
                      const float* __restrict__ w1, const float* __restrict__ b1,
                      const float* __restrict__ w2, const float* __restrict__ b2,
                      const float* __restrict__ w3, const float* __restrict__ b3,
                      _Float16* __restrict__ PWh, _Float16* __restrict__ Wh,
                      float* __restrict__ bc)
{
  const float LOG2E = 1.4426950408889634f;
  const int blk = blockIdx.x;
  if (blk < 704) {
    int idx = blk * 256 + threadIdx.x;
    if (idx < 131072) {
      PWh[idx] = (_Float16)pw[idx];
    } else {
      int j = idx - 131072;
      if (j < 49152) {
        int g = j >> 14, rem = j & 16383;
        const float* wg = (g == 0) ? w1 : (g == 1 ? w2 : w3);
        float v = wg[rem];
        if (g == 0) v *= LOG2E;                      // q in log2 domain
        Wh[j] = (_Float16)v;
      }
    }
  } else {
    int w = threadIdx.x >> 6, lane = threadIdx.x & 63;
    int o3 = (blk - 704) * 4 + w;                    // 0..383
    int g = o3 >> 7, o = o3 & 127;
    const float* wg = (g == 0) ? w1 : (g == 1 ? w2 : w3);
    const float* bg = (g == 0) ? b1 : (g == 1 ? b2 : b3);
    float s = wg[o * 128 + lane] * pb[lane] + wg[o * 128 + 64 + lane] * pb[64 + lane];
    s += __shfl_xor(s, 1);  s += __shfl_xor(s, 2);  s += __shfl_xor(s, 4);
    s += __shfl_xor(s, 8);  s += __shfl_xor(s, 16); s += __shfl_xor(s, 32);
    if (lane == 0) {
      float r = bg[o] + s;
      if (g == 0) r *= LOG2E;
      bc[o3] = r;
    }
  }
}

// ---------------- kernel 1: FUSED featT + gemm1 (R15 version) ----------------
#define FG1_LDS 43008
__global__ __launch_bounds__(256) void k_fg1(const float* __restrict__ feats,
                                             const _Float16* __restrict__ PWh,
                                             _Float16* __restrict__ f2d)
{
  extern __shared__ char smem[];                     // [0,10240): A bufs; [10240,43008): PW bufs
  const int t = threadIdx.x, lane = t & 63, w = t >> 6;
  const int lo = lane & 15, hi = lane >> 4;
  const int n0 = blockIdx.x * 16, b = blockIdx.y;
  const char* pwc = (const char*)PWh;

  float4 areg;
  const int arow = t >> 2, aslot = t & 3;
  auto loadA = [&](int s) {
    areg = *(const float4*)(feats + ((size_t)(b * 1024 + s * 64 + arow)) * 4096 + n0 + aslot * 4);
  };
  auto writeA = [&](int buf) {
    *(float4*)(smem + buf * 5120 + arow * 80 + aslot * 16) = areg;
  };
  auto gllB = [&](int s, int buf) {
    char* base = smem + 10240 + buf * 16384;
    #pragma unroll
    for (int q = 0; q < 4; ++q) {
      int c = w * 4 + q;
      int o = c * 8 + (lane >> 3);
      int slot = lane & 7;
      gll16(pwc + (size_t)o * 2048 + s * 128 + ((slot * 16) ^ ((o & 7) << 4)),
            base + c * 1024);
    }
  };

  const f32x4 zero4 = {0.f, 0.f, 0.f, 0.f};
  f32x4 acc[2];
  acc[0] = zero4; acc[1] = zero4;

  loadA(0); writeA(0); gllB(0, 0);
  for (int s = 0; s < 16; ++s) {
    __syncthreads();
    if (s < 15) { loadA(s + 1); gllB(s + 1, (s + 1) & 1); }
    const char* fb = smem + (s & 1) * 5120;
    const char* pb_ = smem + 10240 + (s & 1) * 16384;
    #pragma unroll
    for (int kk = 0; kk < 2; ++kk) {
      float f0 = *(const float*)(fb + (kk * 32 + hi * 8 + 0) * 80 + lo * 4);
      float f1 = *(const float*)(fb + (kk * 32 + hi * 8 + 1) * 80 + lo * 4);
      float f2 = *(const float*)(fb + (kk * 32 + hi * 8 + 2) * 80 + lo * 4);
      float f3 = *(const float*)(fb + (kk * 32 + hi * 8 + 3) * 80 + lo * 4);
      float f4 = *(const float*)(fb + (kk * 32 + hi * 8 + 4) * 80 + lo * 4);
      float f5 = *(const float*)(fb + (kk * 32 + hi * 8 + 5) * 80 + lo * 4);
      float f6 = *(const float*)(fb + (kk * 32 + hi * 8 + 6) * 80 + lo * 4);
      float f7 = *(const float*)(fb + (kk * 32 + hi * 8 + 7) * 80 + lo * 4);
      u32x4 ua = { __builtin_bit_cast(uint32_t, __builtin_amdgcn_cvt_pkrtz(f0, f1)),
                   __builtin_bit_cast(uint32_t, __builtin_amdgcn_cvt_pkrtz(f2, f3)),
                   __builtin_bit_cast(uint32_t, __builtin_amdgcn_cvt_pkrtz(f4, f5)),
                   __builtin_bit_cast(uint32_t, __builtin_amdgcn_cvt_pkrtz(f6, f7)) };
      h8 af = __builtin_bit_cast(h8, ua);
      h8 bf[2];
      #pragma unroll
      for (int j2 = 0; j2 < 2; ++j2) {
        int o = w * 32 + j2 * 16 + lo;
        bf[j2] = *(const h8*)(pb_ + o * 128 + ((kk * 64 + hi * 16) ^ ((o & 7) << 4)));
      }
      #pragma unroll
      for (int j2 = 0; j2 < 2; ++j2)
        acc[j2] = __builtin_amdgcn_mfma_f32_16x16x32_f16(af, bf[j2], acc[j2], 0, 0, 0);
    }
    if (s < 15) writeA((s + 1) & 1);
  }

  #pragma unroll
  for (int j2 = 0; j2 < 2; ++j2) {
    int o = w * 32 + j2 * 16 + lo;
    #pragma unroll
    for (int r = 0; r < 4; ++r) {
      int n = n0 + hi * 4 + r;
      f2d[((size_t)(b * 4096 + n)) * 128 + o] = (_Float16)acc[j2][r];
    }
  }
}

// ---------------- kernel 2: GEMM2 (R15 version, 512 threads) ----------------
__global__ __launch_bounds__(512) void k_gemm2(const _Float16* __restrict__ f2d,
                                               const _Float16* __restrict__ Wh,
                                               const float* __restrict__ bc,
                                               _Float16* __restrict__ qkvt,
                                               _Float16* __restrict__ vt)
{
  extern __shared__ char smem[];
  const int t = threadIdx.x, lane = t & 63, w = t >> 6;
  const int lo = lane & 15, hi = lane >> 4;
  const int bx = blockIdx.x, n0 = blockIdx.y * 128, b = blockIdx.z;
  const int wr = w >> 1, wc = w & 1;
  const int nb = wr * 32, ob = wc * 64;
  const char* f2c = (const char*)f2d;

  #pragma unroll
  for (int q = 0; q < 4; ++q) {
    int c = w * 4 + q;
    int row = c * 4 + (lane >> 4);
    int col = ((lane & 15) * 16) ^ ((row & 7) << 4);
    gll16(f2c + ((size_t)(b * 4096 + n0 + row)) * 256 + col, smem + c * 1024);
    gll16((const char*)Wh + (size_t)(bx * 128 + row) * 256 + col, smem + 32768 + c * 1024);
  }
  __syncthreads();

  const f32x4 zero4 = {0.f, 0.f, 0.f, 0.f};
  f32x4 acc[2][4];
  #pragma unroll
  for (int i2 = 0; i2 < 2; ++i2)
    #pragma unroll
    for (int j2 = 0; j2 < 4; ++j2) acc[i2][j2] = zero4;

  #pragma unroll
  for (int kk = 0; kk < 4; ++kk) {
    const int cb = kk * 64 + hi * 16;
    h8 af[2], bf[4];
    #pragma unroll
    for (int i2 = 0; i2 < 2; ++i2) {
      int row = nb + i2 * 16 + lo;
      af[i2] = *(const h8*)(smem + row * 256 + (cb ^ ((row & 7) << 4)));
    }
    #pragma unroll
    for (int j2 = 0; j2 < 4; ++j2) {
      int row = ob + j2 * 16 + lo;
      bf[j2] = *(const h8*)(smem + 32768 + row * 256 + (cb ^ ((row & 7) << 4)));
    }
    #pragma unroll
    for (int i2 = 0; i2 < 2; ++i2)
      #pragma unroll
      for (int j2 = 0; j2 < 4; ++j2)
        acc[i2][j2] = __builtin_amdgcn_mfma_f32_16x16x32_f16(af[i2], bf[j2], acc[i2][j2], 0, 0, 0);
  }

  if (bx < 2) {
    #pragma unroll
    for (int j2 = 0; j2 < 4; ++j2) {
      int o = bx * 128 + ob + j2 * 16 + lo;
      float bias = bc[o];
      #pragma unroll
      for (int i2 = 0; i2 < 2; ++i2)
        #pragma unroll
        for (int r = 0; r < 4; ++r) {
          int n = n0 + nb + i2 * 16 + hi * 4 + r;
          qkvt[((size_t)(b * 4096 + n)) * 256 + o] = (_Float16)(acc[i2][j2][r] + bias);
        }
    }
  } else {
    __syncthreads();
    #pragma unroll
    for (int j2 = 0; j2 < 4; ++j2) {
      int o = ob + j2 * 16 + lo;
      float bias = bc[256 + o];
      #pragma unroll
      for (int i2 = 0; i2 < 2; ++i2) {
        int nl = nb + i2 * 16 + hi * 4;
        h4 v4;
        #pragma unroll
        for (int r = 0; r < 4; ++r) v4[r] = (_Float16)(acc[i2][j2][r] + bias);
        *(h4*)(smem + o * 272 + nl * 2) = v4;
      }
    }
    __syncthreads();
    #pragma unroll
    for (int p2 = 0; p2 < 4; ++p2) {
      int i = t + p2 * 512, d = i >> 4, ch = i & 15;
      uint4 v = *(const uint4*)(smem + d * 272 + ch * 16);
      *(uint4*)((char*)vt + ((size_t)(b * 128 + d)) * 8192 + (n0 + ch * 8) * 2) = v;
    }
  }
}

// ---------------- kernel 3: split-KV(x8) flash attention, 32x32x16 (R17 + full residency) ----------------
// grid 1024 = 8p x 4b x 32qt; 256 thr = 4 waves x 32 q = 128 q/block; 16 iters x 32 keys.
// R18 delta: launch_bounds (256,4) -> 4 blocks/CU resident (one pass), 16 waves/CU.
// R17's (256,2) left half the grid queued: 2 blocks/CU, two passes, Occupancy 22%.
// VGPR cap 512/4=128 >= 84 used -> no spill (tripwire: VGPR<=64 or FETCH>>8.2MB => revert).
#define ATT_LDS 32768
__global__ __launch_bounds__(256, 4) void k_attn_part(const _Float16* __restrict__ qkvt,
                                                      const _Float16* __restrict__ vt,
                                                      _Float16* __restrict__ opart,
                                                      float* __restrict__ mlm,
                                                      float* __restrict__ mll)
{
  extern __shared__ char smem[];                     // buf*16K: K[32][256B] ; +8K: V[128][64B]
  const int t = threadIdx.x, lane = t & 63, w = t >> 6;  // w 0..3
  const int q31 = lane & 31, h2 = lane >> 5;
  const int id = blockIdx.x;
  const int vid = (id & 7) * 128 + (id >> 3);        // XCD x gets bp in {4x..4x+3}
  const int qt = vid & 31, bp = vid >> 5;
  const int b = bp >> 3, p = bp & 7;
  const int n0 = qt * 128;
  const char* qbase = (const char*)qkvt + (size_t)b * 4096 * 512;
  const char* vbase = (const char*)vt + (size_t)b * 128 * 8192;

  h8 bq[8];
  {
    const char* qr = qbase + (size_t)(n0 + w * 32 + q31) * 512;
    #pragma unroll
    for (int dk = 0; dk < 8; ++dk) bq[dk] = *(const h8*)(qr + dk * 32 + h2 * 16);
  }

  int koff[2], voff[2], dst_[2];
  #pragma unroll
  for (int i = 0; i < 2; ++i) {
    int idx = t + i * 256;
    int krow = idx >> 4, ks = idx & 15;
    koff[i] = krow * 512 + 256 + ((ks ^ (krow & 7)) * 16);
    int vd = idx >> 2, vs = idx & 3;
    voff[i] = vd * 8192 + ((vs ^ ((vd >> 1) & 3)) * 16);
    dst_[i] = idx * 16;
  }

  auto stage = [&](int m0, int buf) {
    char* kb = smem + buf * 16384;
    char* vb = kb + 8192;
    #pragma unroll
    for (int i = 0; i < 2; ++i) {
      gll16(qbase + (size_t)m0 * 512 + koff[i], kb + dst_[i]);
      gll16(vbase + (size_t)m0 * 2 + voff[i], vb + dst_[i]);
    }
  };

  float m_run = -1e30f, l_run = 0.f;
  f32x16 oacc[4];
  #pragma unroll
  for (int dt = 0; dt < 4; ++dt)
    #pragma unroll
    for (int r = 0; r < 16; ++r) oacc[dt][r] = 0.f;

  const int base = p * 512;
  stage(base, 0);
  __syncthreads();

  for (int it = 0; it < 16; ++it) {
    const int buf = it & 1;
    if (it < 15) stage(base + (it + 1) * 32, buf ^ 1);

    const char* kb = smem + buf * 16384;
    const char* vb = kb + 8192;

    f32x16 s;
    #pragma unroll
    for (int r = 0; r < 16; ++r) s[r] = 0.f;
    #pragma unroll
    for (int dk = 0; dk < 8; ++dk) {
      h8 ak = *(const h8*)(kb + q31 * 256 + (((dk * 2 + h2) ^ (q31 & 7)) * 16));
      s = __builtin_amdgcn_mfma_f32_32x32x16_f16(ak, bq[dk], s, 0, 0, 0);
    }

    // max3-fused depth-3 tree (R14-proven)
    float t0 = fmaxf(fmaxf(s[0],  s[1]),  s[2]);
    float t1 = fmaxf(fmaxf(s[3],  s[4]),  s[5]);
    float t2 = fmaxf(fmaxf(s[6],  s[7]),  s[8]);
    float t3 = fmaxf(fmaxf(s[9],  s[10]), s[11]);
    float t4 = fmaxf(fmaxf(s[12], s[13]), s[14]);
    float mxl = fmaxf(fmaxf(fmaxf(t0, t1), t2), fmaxf(fmaxf(t3, t4), s[15]));
    if (__any(mxl > m_run + 8.f)) {
      float mq = fmaxf(mxl, __shfl_xor(mxl, 32));
      float mnew = fmaxf(m_run, mq);
      float scn = EXP2(m_run - mnew);
      m_run = mnew;
      l_run *= scn;
      #pragma unroll
      for (int dt = 0; dt < 4; ++dt)
        #pragma unroll
        for (int r = 0; r < 16; ++r) oacc[dt][r] *= scn;
    }
    float pv[16];
    #pragma unroll
    for (int r = 0; r < 16; ++r) pv[r] = EXP2(s[r] - m_run);
    // pairwise tree-sum (depth 4)
    float a0 = pv[0] + pv[1],  a1 = pv[2] + pv[3],  a2 = pv[4] + pv[5],  a3 = pv[6] + pv[7];
    float a4 = pv[8] + pv[9],  a5 = pv[10] + pv[11], a6 = pv[12] + pv[13], a7 = pv[14] + pv[15];
    float b0s = a0 + a1, b1s = a2 + a3, b2s = a4 + a5, b3s = a6 + a7;
    l_run += (b0s + b1s) + (b2s + b3s);
    uint32_t wd[8];
    #pragma unroll
    for (int j = 0; j < 8; ++j)
      wd[j] = __builtin_bit_cast(uint32_t, __builtin_amdgcn_cvt_pkrtz(pv[2 * j], pv[2 * j + 1]));

#if HAVE_PLSWAP
    auto r02 = __builtin_amdgcn_permlane32_swap(wd[0], wd[2], false, false);
    auto r13 = __builtin_amdgcn_permlane32_swap(wd[1], wd[3], false, false);
    auto r46 = __builtin_amdgcn_permlane32_swap(wd[4], wd[6], false, false);
    auto r57 = __builtin_amdgcn_permlane32_swap(wd[5], wd[7], false, false);
    u32x4 b0 = { r02[0], r13[0], r02[1], r13[1] };
    u32x4 b1 = { r46[0], r57[0], r46[1], r57[1] };
#else
    uint32_t xw[8];
    #pragma unroll
    for (int j = 0; j < 8; ++j) xw[j] = __shfl_xor(wd[j], 32);
    u32x4 b0 = { h2 ? xw[2] : wd[0], h2 ? xw[3] : wd[1],
                 h2 ? wd[2] : xw[0], h2 ? wd[3] : xw[1] };
    u32x4 b1 = { h2 ? xw[6] : wd[4], h2 ? xw[7] : wd[5],
                 h2 ? wd[6] : xw[4], h2 ? wd[7] : xw[5] };
#endif
    h8 bp0 = __builtin_bit_cast(h8, b0);
    h8 bp1 = __builtin_bit_cast(h8, b1);

    #pragma unroll
    for (int ks = 0; ks < 2; ++ks) {
      h8 bpf = ks ? bp1 : bp0;
      #pragma unroll
      for (int dt = 0; dt < 4; ++dt) {
        int d = dt * 32 + q31;
        h8 av = *(const h8*)(vb + d * 64 + (((ks * 2 + h2) ^ ((d >> 1) & 3)) * 16));
        oacc[dt] = __builtin_amdgcn_mfma_f32_32x32x16_f16(av, bpf, oacc[dt], 0, 0, 0);
      }
    }

    if (it < 15) __syncthreads();
  }

  l_run += __shfl_xor(l_run, 32);
  float invl = 1.0f / l_run;
  _Float16* oph = opart + ((size_t)(p * 4 + b) * 128) * 4096;
  const int ncol = n0 + w * 32 + q31;
  #pragma unroll
  for (int dt = 0; dt < 4; ++dt)
    #pragma unroll
    for (int r = 0; r < 16; ++r) {
      int d = dt * 32 + (r & 3) + 8 * (r >> 2) + 4 * h2;
      oph[(size_t)d * 4096 + ncol] = (_Float16)(oacc[dt][r] * invl);
    }
  if (h2 == 0) {
    size_t mlbase = (size_t)(p * 4 + b) * 4096 + ncol;
    mlm[mlbase] = m_run;
    mll[mlbase] = l_run;
  }
}

// ---------------- kernel 4: combine 8 normalized KV-partials ----------------
__global__ void k_reduce(const _Float16* __restrict__ opart, const float* __restrict__ mlm,
                         const float* __restrict__ mll, float* __restrict__ out)
{
  int idx = blockIdx.x * 256 + threadIdx.x;
  int n4 = idx & 1023, d = (idx >> 10) & 127, b = idx >> 17;
  int n0 = n4 * 4;
  f32x4 m[8], lv[8];
  #pragma unroll
  for (int p = 0; p < 8; ++p) {
    size_t mb = (size_t)(p * 4 + b) * 4096 + n0;
    m[p]  = *(const f32x4*)(mlm + mb);
    lv[p] = *(const f32x4*)(mll + mb);
  }
  f32x4 M = m[0];
  #pragma unroll
  for (int p = 1; p < 8; ++p)
    #pragma unroll
    for (int j = 0; j < 4; ++j) M[j] = fmaxf(M[j], m[p][j]);
  f32x4 denom = {0.f, 0.f, 0.f, 0.f}, num = {0.f, 0.f, 0.f, 0.f};
  #pragma unroll
  for (int p = 0; p < 8; ++p) {
    h4 o = *(const h4*)(opart + ((size_t)((p * 4 + b) * 128 + d)) * 4096 + n0);
    #pragma unroll
    for (int j = 0; j < 4; ++j) {
      float wgt = lv[p][j] * EXP2(m[p][j] - M[j]);
      denom[j] += wgt;
      num[j]   += (float)o[j] * wgt;
    }
  }
  f32x4 r;
  #pragma unroll
  for (int j = 0; j < 4; ++j) r[j] = num[j] / denom[j];
  *(f32x4*)(out + ((size_t)(b * 128 + d)) * 4096 + n0) = r;
}

extern "C" void kernel_launch(void* const* d_in, const int* in_sizes, int n_in,
                              void* d_out, int out_size, void* d_ws, size_t ws_size,
                              hipStream_t stream)
{
  const float* feats = (const float*)d_in[0];
  const float* pw = (const float*)d_in[1];
  const float* pb = (const float*)d_in[2];
  const float* w1 = (const float*)d_in[3];
  const float* b1 = (const float*)d_in[4];
  const float* w2 = (const float*)d_in[5];
  const float* b2 = (const float*)d_in[6];
  const float* w3 = (const float*)d_in[7];
  const float* b3 = (const float*)d_in[8];
  char* ws = (char*)d_ws;
  _Float16* PWh = (_Float16*)(ws + WS_PWH);
  _Float16* Wh = (_Float16*)(ws + WS_WH);
  float* bc = (float*)(ws + WS_BC);
  _Float16* f2d = (_Float16*)(ws + WS_F2D);
  _Float16* qkvt = (_Float16*)(ws + WS_QKVT);
  _Float16* vt = (_Float16*)(ws + WS_VT);
  _Float16* opart = (_Float16*)(ws + WS_OP);
  float* mlm = (float*)(ws + WS_MLM);
  float* mll = (float*)(ws + WS_MLL);
  float* out = (float*)d_out;

  hipLaunchKernelGGL(k_cvt, dim3(800), dim3(256), 0, stream,
                     pw, pb, w1, b1, w2, b2, w3, b3, PWh, Wh, bc);
  hipLaunchKernelGGL(k_fg1, dim3(256, 4), dim3(256), FG1_LDS, stream, feats, PWh, f2d);
  hipLaunchKernelGGL(k_gemm2, dim3(3, 32, 4), dim3(512), 65536, stream, f2d, Wh, bc, qkvt, vt);
  hipLaunchKernelGGL(k_attn_part, dim3(1024), dim3(256), ATT_LDS, stream, qkvt, vt, opart, mlm, mll);
  hipLaunchKernelGGL(k_reduce, dim3(2048), dim3(256), 0, stream, opart, mlm, mll, out);
}

// Round 19
// 97.137 us; speedup vs baseline: 1.4544x; 1.4544x over previous
//
#include <hip/hip_runtime.h>
#include <stdint.h>

typedef _Float16 h8 __attribute__((ext_vector_type(8)));
typedef _Float16 h4 __attribute__((ext_vector_type(4)));
typedef float f32x4 __attribute__((ext_vector_type(4)));
typedef float f32x16 __attribute__((ext_vector_type(16)));
typedef uint32_t u32x4 __attribute__((ext_vector_type(4)));

#if __has_builtin(__builtin_amdgcn_exp2f)
#define EXP2(x) __builtin_amdgcn_exp2f(x)
#else
#define EXP2(x) exp2f(x)
#endif

#if __has_builtin(__builtin_amdgcn_permlane32_swap)
#define HAVE_PLSWAP 1
#else
#define HAVE_PLSWAP 0
#endif

// workspace map (total <= 51380224 bytes)
#define WS_PWH  0u          // _Float16 [128][1024]  (dead after fg1; mlm overwrites)
#define WS_WH   262144u     // _Float16 [384][128]   (dead after gemm2)
#define WS_BC   600064u     // float [384]
#define WS_F2D  1048576u    // _Float16 [4][4096][128] dense (dead after gemm2)
#define WS_OP   5242880u    // _Float16 [16 pb][128 d][4096 n] normalized partial O (16.8MB)
#define WS_QKVT 38797312u   // _Float16 [4][4096][256] q|k, 512B rows
#define WS_VT   47185920u   // _Float16 [4][128][4096] v, d-major
#define WS_MLM  0u          // float [16][4096] running max (log2 domain)
#define WS_MLL  262144u     // float [16][4096] running sum

__device__ __forceinline__ void gll16(const void* g, void* l) {
  __builtin_amdgcn_global_load_lds((const __attribute__((address_space(1))) unsigned int*)g,
                                   (__attribute__((address_space(3))) unsigned int*)l, 16, 0, 0);
}

// ---------------- kernel 0: casts; bias bc = b + W*pb via one WAVE per o ----------------
__global__ void k_cvt(const float* __restrict__ pw, const float* __restrict__ pb,
                      const float* __restrict__ w1, const float* __restrict__ b1,
                      const float* __restrict__ w2, const float* __restrict__ b2,
                      const float* __restrict__ w3, const float* __restrict__ b3,
                      _Float16* __restrict__ PWh, _Float16* __restrict__ Wh,
                      float* __restrict__ bc)
{
  const float LOG2E = 1.4426950408889634f;
  const int blk = blockIdx.x;
  if (blk < 704) {
    int idx = blk * 256 + threadIdx.x;
    if (idx < 131072) {
      PWh[idx] = (_Float16)pw[idx];
    } else {
      int j = idx - 131072;
      if (j < 49152) {
        int g = j >> 14, rem = j & 16383;
        const float* wg = (g == 0) ? w1 : (g == 1 ? w2 : w3);
        float v = wg[rem];
        if (g == 0) v *= LOG2E;                      // q in log2 domain
        Wh[j] = (_Float16)v;
      }
    }
  } else {
    int w = threadIdx.x >> 6, lane = threadIdx.x & 63;
    int o3 = (blk - 704) * 4 + w;                    // 0..383
    int g = o3 >> 7, o = o3 & 127;
    const float* wg = (g == 0) ? w1 : (g == 1 ? w2 : w3);
    const float* bg = (g == 0) ? b1 : (g == 1 ? b2 : b3);
    float s = wg[o * 128 + lane] * pb[lane] + wg[o * 128 + 64 + lane] * pb[64 + lane];
    s += __shfl_xor(s, 1);  s += __shfl_xor(s, 2);  s += __shfl_xor(s, 4);
    s += __shfl_xor(s, 8);  s += __shfl_xor(s, 16); s += __shfl_xor(s, 32);
    if (lane == 0) {
      float r = bg[o] + s;
      if (g == 0) r *= LOG2E;
      bc[o3] = r;
    }
  }
}

// ---------------- kernel 1: FUSED featT + gemm1 (R15 version) ----------------
#define FG1_LDS 43008
__global__ __launch_bounds__(256) void k_fg1(const float* __restrict__ feats,
                                             const _Float16* __restrict__ PWh,
                                             _Float16* __restrict__ f2d)
{
  extern __shared__ char smem[];                     // [0,10240): A bufs; [10240,43008): PW bufs
  const int t = threadIdx.x, lane = t & 63, w = t >> 6;
  const int lo = lane & 15, hi = lane >> 4;
  const int n0 = blockIdx.x * 16, b = blockIdx.y;
  const char* pwc = (const char*)PWh;

  float4 areg;
  const int arow = t >> 2, aslot = t & 3;
  auto loadA = [&](int s) {
    areg = *(const float4*)(feats + ((size_t)(b * 1024 + s * 64 + arow)) * 4096 + n0 + aslot * 4);
  };
  auto writeA = [&](int buf) {
    *(float4*)(smem + buf * 5120 + arow * 80 + aslot * 16) = areg;
  };
  auto gllB = [&](int s, int buf) {
    char* base = smem + 10240 + buf * 16384;
    #pragma unroll
    for (int q = 0; q < 4; ++q) {
      int c = w * 4 + q;
      int o = c * 8 + (lane >> 3);
      int slot = lane & 7;
      gll16(pwc + (size_t)o * 2048 + s * 128 + ((slot * 16) ^ ((o & 7) << 4)),
            base + c * 1024);
    }
  };

  const f32x4 zero4 = {0.f, 0.f, 0.f, 0.f};
  f32x4 acc[2];
  acc[0] = zero4; acc[1] = zero4;

  loadA(0); writeA(0); gllB(0, 0);
  for (int s = 0; s < 16; ++s) {
    __syncthreads();
    if (s < 15) { loadA(s + 1); gllB(s + 1, (s + 1) & 1); }
    const char* fb = smem + (s & 1) * 5120;
    const char* pb_ = smem + 10240 + (s & 1) * 16384;
    #pragma unroll
    for (int kk = 0; kk < 2; ++kk) {
      float f0 = *(const float*)(fb + (kk * 32 + hi * 8 + 0) * 80 + lo * 4);
      float f1 = *(const float*)(fb + (kk * 32 + hi * 8 + 1) * 80 + lo * 4);
      float f2 = *(const float*)(fb + (kk * 32 + hi * 8 + 2) * 80 + lo * 4);
      float f3 = *(const float*)(fb + (kk * 32 + hi * 8 + 3) * 80 + lo * 4);
      float f4 = *(const float*)(fb + (kk * 32 + hi * 8 + 4) * 80 + lo * 4);
      float f5 = *(const float*)(fb + (kk * 32 + hi * 8 + 5) * 80 + lo * 4);
      float f6 = *(const float*)(fb + (kk * 32 + hi * 8 + 6) * 80 + lo * 4);
      float f7 = *(const float*)(fb + (kk * 32 + hi * 8 + 7) * 80 + lo * 4);
      u32x4 ua = { __builtin_bit_cast(uint32_t, __builtin_amdgcn_cvt_pkrtz(f0, f1)),
                   __builtin_bit_cast(uint32_t, __builtin_amdgcn_cvt_pkrtz(f2, f3)),
                   __builtin_bit_cast(uint32_t, __builtin_amdgcn_cvt_pkrtz(f4, f5)),
                   __builtin_bit_cast(uint32_t, __builtin_amdgcn_cvt_pkrtz(f6, f7)) };
      h8 af = __builtin_bit_cast(h8, ua);
      h8 bf[2];
      #pragma unroll
      for (int j2 = 0; j2 < 2; ++j2) {
        int o = w * 32 + j2 * 16 + lo;
        bf[j2] = *(const h8*)(pb_ + o * 128 + ((kk * 64 + hi * 16) ^ ((o & 7) << 4)));
      }
      #pragma unroll
      for (int j2 = 0; j2 < 2; ++j2)
        acc[j2] = __builtin_amdgcn_mfma_f32_16x16x32_f16(af, bf[j2], acc[j2], 0, 0, 0);
    }
    if (s < 15) writeA((s + 1) & 1);
  }

  #pragma unroll
  for (int j2 = 0; j2 < 2; ++j2) {
    int o = w * 32 + j2 * 16 + lo;
    #pragma unroll
    for (int r = 0; r < 4; ++r) {
      int n = n0 + hi * 4 + r;
      f2d[((size_t)(b * 4096 + n)) * 128 + o] = (_Float16)acc[j2][r];
    }
  }
}

// ---------------- kernel 2: GEMM2 (R15 version, 512 threads) ----------------
__global__ __launch_bounds__(512) void k_gemm2(const _Float16* __restrict__ f2d,
                                               const _Float16* __restrict__ Wh,
                                               const float* __restrict__ bc,
                                               _Float16* __restrict__ qkvt,
                                               _Float16* __restrict__ vt)
{
  extern __shared__ char smem[];
  const int t = threadIdx.x, lane = t & 63, w = t >> 6;
  const int lo = lane & 15, hi = lane >> 4;
  const int bx = blockIdx.x, n0 = blockIdx.y * 128, b = blockIdx.z;
  const int wr = w >> 1, wc = w & 1;
  const int nb = wr * 32, ob = wc * 64;
  const char* f2c = (const char*)f2d;

  #pragma unroll
  for (int q = 0; q < 4; ++q) {
    int c = w * 4 + q;
    int row = c * 4 + (lane >> 4);
    int col = ((lane & 15) * 16) ^ ((row & 7) << 4);
    gll16(f2c + ((size_t)(b * 4096 + n0 + row)) * 256 + col, smem + c * 1024);
    gll16((const char*)Wh + (size_t)(bx * 128 + row) * 256 + col, smem + 32768 + c * 1024);
  }
  __syncthreads();

  const f32x4 zero4 = {0.f, 0.f, 0.f, 0.f};
  f32x4 acc[2][4];
  #pragma unroll
  for (int i2 = 0; i2 < 2; ++i2)
    #pragma unroll
    for (int j2 = 0; j2 < 4; ++j2) acc[i2][j2] = zero4;

  #pragma unroll
  for (int kk = 0; kk < 4; ++kk) {
    const int cb = kk * 64 + hi * 16;
    h8 af[2], bf[4];
    #pragma unroll
    for (int i2 = 0; i2 < 2; ++i2) {
      int row = nb + i2 * 16 + lo;
      af[i2] = *(const h8*)(smem + row * 256 + (cb ^ ((row & 7) << 4)));
    }
    #pragma unroll
    for (int j2 = 0; j2 < 4; ++j2) {
      int row = ob + j2 * 16 + lo;
      bf[j2] = *(const h8*)(smem + 32768 + row * 256 + (cb ^ ((row & 7) << 4)));
    }
    #pragma unroll
    for (int i2 = 0; i2 < 2; ++i2)
      #pragma unroll
      for (int j2 = 0; j2 < 4; ++j2)
        acc[i2][j2] = __builtin_amdgcn_mfma_f32_16x16x32_f16(af[i2], bf[j2], acc[i2][j2], 0, 0, 0);
  }

  if (bx < 2) {
    #pragma unroll
    for (int j2 = 0; j2 < 4; ++j2) {
      int o = bx * 128 + ob + j2 * 16 + lo;
      float bias = bc[o];
      #pragma unroll
      for (int i2 = 0; i2 < 2; ++i2)
        #pragma unroll
        for (int r = 0; r < 4; ++r) {
          int n = n0 + nb + i2 * 16 + hi * 4 + r;
          qkvt[((size_t)(b * 4096 + n)) * 256 + o] = (_Float16)(acc[i2][j2][r] + bias);
        }
    }
  } else {
    __syncthreads();
    #pragma unroll
    for (int j2 = 0; j2 < 4; ++j2) {
      int o = ob + j2 * 16 + lo;
      float bias = bc[256 + o];
      #pragma unroll
      for (int i2 = 0; i2 < 2; ++i2) {
        int nl = nb + i2 * 16 + hi * 4;
        h4 v4;
        #pragma unroll
        for (int r = 0; r < 4; ++r) v4[r] = (_Float16)(acc[i2][j2][r] + bias);
        *(h4*)(smem + o * 272 + nl * 2) = v4;
      }
    }
    __syncthreads();
    #pragma unroll
    for (int p2 = 0; p2 < 4; ++p2) {
      int i = t + p2 * 512, d = i >> 4, ch = i & 15;
      uint4 v = *(const uint4*)(smem + d * 272 + ch * 16);
      *(uint4*)((char*)vt + ((size_t)(b * 128 + d)) * 8192 + (n0 + ch * 8) * 2) = v;
    }
  }
}

// ---------------- kernel 3: split-KV(x4) flash attention, 32x32x16 (R17 kernel, split 8->4) ----------------
// grid 512 = 4p x 4b x 32qt; 256 thr = 4 waves x 32 q = 128 q/block; 32 iters x 32 keys.
// launch_bounds (256,2): true reg footprint (VGPR+AGPR unified) > 128 -> (256,4) spilled (R18:
// VGPR 64, 66MB FETCH). (256,2) verified 51.2us. Split 4 halves opart/reduce traffic; grid 512
// = exactly 2 blocks/CU resident in one pass.
#define ATT_LDS 32768
__global__ __launch_bounds__(256, 2) void k_attn_part(const _Float16* __restrict__ qkvt,
                                                      const _Float16* __restrict__ vt,
                                                      _Float16* __restrict__ opart,
                                                      float* __restrict__ mlm,
                                                      float* __restrict__ mll)
{
  extern __shared__ char smem[];                     // buf*16K: K[32][256B] ; +8K: V[128][64B]
  const int t = threadIdx.x, lane = t & 63, w = t >> 6;  // w 0..3
  const int q31 = lane & 31, h2 = lane >> 5;
  const int id = blockIdx.x;
  const int vid = (id & 7) * 64 + (id >> 3);         // XCD x gets vid in [x*64,(x+1)*64)
  const int qt = vid & 31, bp = vid >> 5;            // bp 0..15 = p*4+b; 2 bp per XCD
  const int b = bp & 3, p = bp >> 2;
  const int n0 = qt * 128;
  const char* qbase = (const char*)qkvt + (size_t)b * 4096 * 512;
  const char* vbase = (const char*)vt + (size_t)b * 128 * 8192;

  h8 bq[8];
  {
    const char* qr = qbase + (size_t)(n0 + w * 32 + q31) * 512;
    #pragma unroll
    for (int dk = 0; dk < 8; ++dk) bq[dk] = *(const h8*)(qr + dk * 32 + h2 * 16);
  }

  int koff[2], voff[2], dst_[2];
  #pragma unroll
  for (int i = 0; i < 2; ++i) {
    int idx = t + i * 256;
    int krow = idx >> 4, ks = idx & 15;
    koff[i] = krow * 512 + 256 + ((ks ^ (krow & 7)) * 16);
    int vd = idx >> 2, vs = idx & 3;
    voff[i] = vd * 8192 + ((vs ^ ((vd >> 1) & 3)) * 16);
    dst_[i] = idx * 16;
  }

  auto stage = [&](int m0, int buf) {
    char* kb = smem + buf * 16384;
    char* vb = kb + 8192;
    #pragma unroll
    for (int i = 0; i < 2; ++i) {
      gll16(qbase + (size_t)m0 * 512 + koff[i], kb + dst_[i]);
      gll16(vbase + (size_t)m0 * 2 + voff[i], vb + dst_[i]);
    }
  };

  float m_run = -1e30f, l_run = 0.f;
  f32x16 oacc[4];
  #pragma unroll
  for (int dt = 0; dt < 4; ++dt)
    #pragma unroll
    for (int r = 0; r < 16; ++r) oacc[dt][r] = 0.f;

  const int base = p * 1024;
  stage(base, 0);
  __syncthreads();

  for (int it = 0; it < 32; ++it) {
    const int buf = it & 1;
    if (it < 31) stage(base + (it + 1) * 32, buf ^ 1);

    const char* kb = smem + buf * 16384;
    const char* vb = kb + 8192;

    f32x16 s;
    #pragma unroll
    for (int r = 0; r < 16; ++r) s[r] = 0.f;
    #pragma unroll
    for (int dk = 0; dk < 8; ++dk) {
      h8 ak = *(const h8*)(kb + q31 * 256 + (((dk * 2 + h2) ^ (q31 & 7)) * 16));
      s = __builtin_amdgcn_mfma_f32_32x32x16_f16(ak, bq[dk], s, 0, 0, 0);
    }

    // max3-fused depth-3 tree (R14-proven)
    float t0 = fmaxf(fmaxf(s[0],  s[1]),  s[2]);
    float t1 = fmaxf(fmaxf(s[3],  s[4]),  s[5]);
    float t2 = fmaxf(fmaxf(s[6],  s[7]),  s[8]);
    float t3 = fmaxf(fmaxf(s[9],  s[10]), s[11]);
    float t4 = fmaxf(fmaxf(s[12], s[13]), s[14]);
    float mxl = fmaxf(fmaxf(fmaxf(t0, t1), t2), fmaxf(fmaxf(t3, t4), s[15]));
    if (__any(mxl > m_run + 8.f)) {
      float mq = fmaxf(mxl, __shfl_xor(mxl, 32));
      float mnew = fmaxf(m_run, mq);
      float scn = EXP2(m_run - mnew);
      m_run = mnew;
      l_run *= scn;
      #pragma unroll
      for (int dt = 0; dt < 4; ++dt)
        #pragma unroll
        for (int r = 0; r < 16; ++r) oacc[dt][r] *= scn;
    }
    float pv[16];
    #pragma unroll
    for (int r = 0; r < 16; ++r) pv[r] = EXP2(s[r] - m_run);
    // pairwise tree-sum (depth 4)
    float a0 = pv[0] + pv[1],  a1 = pv[2] + pv[3],  a2 = pv[4] + pv[5],  a3 = pv[6] + pv[7];
    float a4 = pv[8] + pv[9],  a5 = pv[10] + pv[11], a6 = pv[12] + pv[13], a7 = pv[14] + pv[15];
    float b0s = a0 + a1, b1s = a2 + a3, b2s = a4 + a5, b3s = a6 + a7;
    l_run += (b0s + b1s) + (b2s + b3s);
    uint32_t wd[8];
    #pragma unroll
    for (int j = 0; j < 8; ++j)
      wd[j] = __builtin_bit_cast(uint32_t, __builtin_amdgcn_cvt_pkrtz(pv[2 * j], pv[2 * j + 1]));

#if HAVE_PLSWAP
    auto r02 = __builtin_amdgcn_permlane32_swap(wd[0], wd[2], false, false);
    auto r13 = __builtin_amdgcn_permlane32_swap(wd[1], wd[3], false, false);
    auto r46 = __builtin_amdgcn_permlane32_swap(wd[4], wd[6], false, false);
    auto r57 = __builtin_amdgcn_permlane32_swap(wd[5], wd[7], false, false);
    u32x4 b0 = { r02[0], r13[0], r02[1], r13[1] };
    u32x4 b1 = { r46[0], r57[0], r46[1], r57[1] };
#else
    uint32_t xw[8];
    #pragma unroll
    for (int j = 0; j < 8; ++j) xw[j] = __shfl_xor(wd[j], 32);
    u32x4 b0 = { h2 ? xw[2] : wd[0], h2 ? xw[3] : wd[1],
                 h2 ? wd[2] : xw[0], h2 ? wd[3] : xw[1] };
    u32x4 b1 = { h2 ? xw[6] : wd[4], h2 ? xw[7] : wd[5],
                 h2 ? wd[6] : xw[4], h2 ? wd[7] : xw[5] };
#endif
    h8 bp0 = __builtin_bit_cast(h8, b0);
    h8 bp1 = __builtin_bit_cast(h8, b1);

    #pragma unroll
    for (int ks = 0; ks < 2; ++ks) {
      h8 bpf = ks ? bp1 : bp0;
      #pragma unroll
      for (int dt = 0; dt < 4; ++dt) {
        int d = dt * 32 + q31;
        h8 av = *(const h8*)(vb + d * 64 + (((ks * 2 + h2) ^ ((d >> 1) & 3)) * 16));
        oacc[dt] = __builtin_amdgcn_mfma_f32_32x32x16_f16(av, bpf, oacc[dt], 0, 0, 0);
      }
    }

    if (it < 31) __syncthreads();
  }

  l_run += __shfl_xor(l_run, 32);
  float invl = 1.0f / l_run;
  _Float16* oph = opart + ((size_t)bp * 128) * 4096;
  const int ncol = n0 + w * 32 + q31;
  #pragma unroll
  for (int dt = 0; dt < 4; ++dt)
    #pragma unroll
    for (int r = 0; r < 16; ++r) {
      int d = dt * 32 + (r & 3) + 8 * (r >> 2) + 4 * h2;
      oph[(size_t)d * 4096 + ncol] = (_Float16)(oacc[dt][r] * invl);
    }
  if (h2 == 0) {
    size_t mlbase = (size_t)bp * 4096 + ncol;
    mlm[mlbase] = m_run;
    mll[mlbase] = l_run;
  }
}

// ---------------- kernel 4: combine 4 normalized KV-partials ----------------
__global__ void k_reduce(const _Float16* __restrict__ opart, const float* __restrict__ mlm,
                         const float* __restrict__ mll, float* __restrict__ out)
{
  int idx = blockIdx.x * 256 + threadIdx.x;
  int n4 = idx & 1023, d = (idx >> 10) & 127, b = idx >> 17;
  int n0 = n4 * 4;
  f32x4 m[4], lv[4];
  #pragma unroll
  for (int p = 0; p < 4; ++p) {
    size_t mb = (size_t)(p * 4 + b) * 4096 + n0;
    m[p]  = *(const f32x4*)(mlm + mb);
    lv[p] = *(const f32x4*)(mll + mb);
  }
  f32x4 M = m[0];
  #pragma unroll
  for (int p = 1; p < 4; ++p)
    #pragma unroll
    for (int j = 0; j < 4; ++j) M[j] = fmaxf(M[j], m[p][j]);
  f32x4 denom = {0.f, 0.f, 0.f, 0.f}, num = {0.f, 0.f, 0.f, 0.f};
  #pragma unroll
  for (int p = 0; p < 4; ++p) {
    h4 o = *(const h4*)(opart + ((size_t)((p * 4 + b) * 128 + d)) * 4096 + n0);
    #pragma unroll
    for (int j = 0; j < 4; ++j) {
      float wgt = lv[p][j] * EXP2(m[p][j] - M[j]);
      denom[j] += wgt;
      num[j]   += (float)o[j] * wgt;
    }
  }
  f32x4 r;
  #pragma unroll
  for (int j = 0; j < 4; ++j) r[j] = num[j] / denom[j];
  *(f32x4*)(out + ((size_t)(b * 128 + d)) * 4096 + n0) = r;
}

extern "C" void kernel_launch(void* const* d_in, const int* in_sizes, int n_in,
                              void* d_out, int out_size, void* d_ws, size_t ws_size,
                              hipStream_t stream)
{
  const float* feats = (const float*)d_in[0];
  const float* pw = (const float*)d_in[1];
  const float* pb = (const float*)d_in[2];
  const float* w1 = (const float*)d_in[3];
  const float* b1 = (const float*)d_in[4];
  const float* w2 = (const float*)d_in[5];
  const float* b2 = (const float*)d_in[6];
  const float* w3 = (const float*)d_in[7];
  const float* b3 = (const float*)d_in[8];
  char* ws = (char*)d_ws;
  _Float16* PWh = (_Float16*)(ws + WS_PWH);
  _Float16* Wh = (_Float16*)(ws + WS_WH);
  float* bc = (float*)(ws + WS_BC);
  _Float16* f2d = (_Float16*)(ws + WS_F2D);
  _Float16* qkvt = (_Float16*)(ws + WS_QKVT);
  _Float16* vt = (_Float16*)(ws + WS_VT);
  _Float16* opart = (_Float16*)(ws + WS_OP);
  float* mlm = (float*)(ws + WS_MLM);
  float* mll = (float*)(ws + WS_MLL);
  float* out = (float*)d_out;

  hipLaunchKernelGGL(k_cvt, dim3(800), dim3(256), 0, stream,
                     pw, pb, w1, b1, w2, b2, w3, b3, PWh, Wh, bc);
  hipLaunchKernelGGL(k_fg1, dim3(256, 4), dim3(256), FG1_LDS, stream, feats, PWh, f2d);
  hipLaunchKernelGGL(k_gemm2, dim3(3, 32, 4), dim3(512), 65536, stream, f2d, Wh, bc, qkvt, vt);
  hipLaunchKernelGGL(k_attn_part, dim3(512), dim3(256), ATT_LDS, stream, qkvt, vt, opart, mlm, mll);
  hipLaunchKernelGGL(k_reduce, dim3(2048), dim3(256), 0, stream, opart, mlm, mll, out);
}